// Round 8
// baseline (335.659 us; speedup 1.0000x reference)
//
#include <hip/hip_runtime.h>

// VQ nearest-codebook argmin — single-pass bf16 MFMA + exact rescore.
//
// Pass 1: G ≈ zh.eh (one bf16 MFMA pass). |2G - 2G_exact| tail ≈ 6e-5.
//   Rows with measured top-2 gap <= TAU=4e-4 get rescored (ref slack ~1.3e-4,
//   bf16 noise ~2.5e-5 sigma -> 22-sigma coverage).
// Pass 2 (LOCKED numerics, rounds 3-7, absmax 0): numpy-fp32 bit semantics:
//   s1,s2 pairwise fp32 sums of squares; G fp64 -> fl32(2G);
//   d = fl32(fl32(s1-2G)+s2); argmin, first-index tie-break.

#define DDIM 256
#define KCODES 1024
#define TAU 4e-4f
#define LISTCAP 16384

typedef __attribute__((ext_vector_type(8))) short bf16x8;
typedef __attribute__((ext_vector_type(4))) float f32x4;
typedef __attribute__((ext_vector_type(8))) unsigned short u16x8;

__device__ __forceinline__ unsigned short f2bf(float f) {
    unsigned int u = __builtin_bit_cast(unsigned int, f);
    u += 0x7FFFu + ((u >> 16) & 1u);
    return (unsigned short)(u >> 16);
}

// ---------- locked numerics helper (rounds 3-7, do not touch) ----------
__device__ __forceinline__ float block128_sq(const float* __restrict__ a)
{
#pragma clang fp contract(off)
    float r[8];
    #pragma unroll
    for (int j = 0; j < 8; ++j) { float v = a[j]; r[j] = v * v; }
    #pragma unroll
    for (int i = 8; i < 128; i += 8) {
        #pragma unroll
        for (int j = 0; j < 8; ++j) { float v = a[i + j]; r[j] = r[j] + v * v; }
    }
    return ((r[0] + r[1]) + (r[2] + r[3])) + ((r[4] + r[5]) + (r[6] + r[7]));
}

// ---- prep: emb -> bf16 (eh), s2 pairwise, count reset. grid 128 x 256 ----
__global__ __launch_bounds__(256) void vq_prep(
    const float* __restrict__ emb, unsigned short* __restrict__ eh,
    float* __restrict__ s2, int* __restrict__ count)
{
    const int tid = threadIdx.x;
    if (blockIdx.x == 0 && tid == 0) *count = 0;

    const int id = blockIdx.x * 256 + tid;            // ushort8 chunk, 32768 total
    const float* src = emb + (size_t)id * 8;
    float4 p0 = *reinterpret_cast<const float4*>(src);
    float4 p1 = *reinterpret_cast<const float4*>(src + 4);
    float fv[8] = {p0.x, p0.y, p0.z, p0.w, p1.x, p1.y, p1.z, p1.w};
    u16x8 vh;
    #pragma unroll
    for (int e = 0; e < 8; ++e) vh[e] = f2bf(fv[e]);
    *reinterpret_cast<u16x8*>(eh + (size_t)id * 8) = vh;

    if (tid < 8) {                                    // 8 codes per block
        const int c = blockIdx.x * 8 + tid;
        const float* e = emb + (size_t)c * DDIM;
        s2[c] = block128_sq(e) + block128_sq(e + 128);
    }
}

// ---------------------------- pass 1 (bf16 MFMA) ----------------------------
// 256 thr = 4 waves: wave (rowHalf = wid&1, codeHalf = wid>>1) handles
// 32 rows x 512 codes. B tiles [128 codes][32 k] double-buffered per half,
// chunk-swizzled (round-7 scheme, 0 conflicts measured).
__global__ __launch_bounds__(256, 2) void vq_pass1(
    const float* __restrict__ z, const unsigned short* __restrict__ eh,
    const float* __restrict__ s2g, int* __restrict__ out,
    int* __restrict__ count, int* __restrict__ list, int N)
{
    __shared__ __align__(16) unsigned short Bt[2][2][4096]; // [dbuf][half][128x32]
    __shared__ float s2s[KCODES];
    __shared__ float Lbv[2][64], Lsv[2][64];
    __shared__ int   Lbk[2][64];

    const int tid  = threadIdx.x;
    const int wid  = tid >> 6, lane = tid & 63;
    const int ll   = lane & 15, lg = lane >> 4;
    const int rowHalf  = wid & 1, codeHalf = wid >> 1;
    const int rowbase  = blockIdx.x * 64 + rowHalf * 32;
    const int chbase   = codeHalf * 512;

    for (int c = tid; c < KCODES; c += 256) s2s[c] = s2g[c];

    const int sB     = (ll >> 1) & 3;
    const int rdbase = ll * 32 + ((lg ^ sB) << 3);

    // staging helper data: thread's 4 chunks, id = q*256+tid in [0,1024)
    //   half = id>>9, cl = (id&511)>>2, pc = id&3, clog = pc ^ ((cl>>1)&3)
    // write linear (byte off = id*16 within [half] region); swizzle on source.

    bf16x8 afrag[8][2];
    f32x4  acc[2][8];
    float  bv[2][4], sv[2][4];
    int    bk[2][4];
    #pragma unroll
    for (int m = 0; m < 2; ++m)
        #pragma unroll
        for (int j = 0; j < 4; ++j) { bv[m][j] = 3.4e38f; sv[m][j] = 3.4e38f; bk[m][j] = 0; }

    // prologue: stage (ct=0, ks=0) into buf 0
    {
        #pragma unroll
        for (int q = 0; q < 4; ++q) {
            int id = q * 256 + tid;
            int half = id >> 9, rem = id & 511, cl = rem >> 2, pc = rem & 3;
            int clog = pc ^ ((cl >> 1) & 3);
            u16x8 v = *reinterpret_cast<const u16x8*>(
                eh + (size_t)(half * 512 + cl) * DDIM + clog * 8);
            *reinterpret_cast<u16x8*>(&Bt[0][half][cl * 32 + pc * 8]) = v;
        }
    }
    __syncthreads();

    for (int ct = 0; ct < 4; ++ct) {
        const f32x4 zero4 = {0.f, 0.f, 0.f, 0.f};
        #pragma unroll
        for (int m = 0; m < 2; ++m)
            #pragma unroll
            for (int n = 0; n < 8; ++n) acc[m][n] = zero4;

        #pragma unroll
        for (int ks = 0; ks < 8; ++ks) {
            const int buf = ks & 1;
            const int t   = ct * 8 + ks;
            const bool hasNext = (t < 31);

            // issue next tile pair's global loads early
            u16x8 sb[4];
            if (hasNext) {
                const int nt = t + 1, nct = nt >> 3, nks = nt & 7;
                #pragma unroll
                for (int q = 0; q < 4; ++q) {
                    int id = q * 256 + tid;
                    int half = id >> 9, rem = id & 511, cl = rem >> 2, pc = rem & 3;
                    int clog = pc ^ ((cl >> 1) & 3);
                    sb[q] = *reinterpret_cast<const u16x8*>(
                        eh + (size_t)(half * 512 + nct * 128 + cl) * DDIM + nks * 32 + clog * 8);
                }
            }

            // A-frags: convert once (ct==0), reuse for ct=1..3 (static ks index)
            if (ct == 0) {
                #pragma unroll
                for (int m = 0; m < 2; ++m) {
                    const float* zp = z + (size_t)(rowbase + 16 * m + ll) * DDIM + ks * 32 + lg * 8;
                    float4 p0 = *reinterpret_cast<const float4*>(zp);
                    float4 p1 = *reinterpret_cast<const float4*>(zp + 4);
                    float fv[8] = {p0.x, p0.y, p0.z, p0.w, p1.x, p1.y, p1.z, p1.w};
                    #pragma unroll
                    for (int e = 0; e < 8; ++e) afrag[ks][m][e] = (short)f2bf(fv[e]);
                }
            }

            #pragma unroll
            for (int n = 0; n < 8; ++n) {
                bf16x8 bh = *reinterpret_cast<const bf16x8*>(
                    &Bt[buf][codeHalf][n * 512 + rdbase]);
                #pragma unroll
                for (int m = 0; m < 2; ++m)
                    acc[m][n] = __builtin_amdgcn_mfma_f32_16x16x32_bf16(
                        afrag[ks][m], bh, acc[m][n], 0, 0, 0);
            }

            if (ks == 7) {      // fold ct-tile into running top-2
                #pragma unroll
                for (int n = 0; n < 8; ++n) {
                    const int c = chbase + ct * 128 + n * 16 + ll;
                    const float s2v = s2s[c];
                    #pragma unroll
                    for (int m = 0; m < 2; ++m)
                        #pragma unroll
                        for (int j = 0; j < 4; ++j) {
                            float v = fmaf(-2.0f, acc[m][n][j], s2v);
                            if (v < bv[m][j] || (v == bv[m][j] && c < bk[m][j])) {
                                sv[m][j] = bv[m][j]; bv[m][j] = v; bk[m][j] = c;
                            } else {
                                sv[m][j] = fminf(sv[m][j], v);
                            }
                        }
                }
            }

            if (hasNext) {
                const int nbuf = buf ^ 1;
                #pragma unroll
                for (int q = 0; q < 4; ++q) {
                    int id = q * 256 + tid;
                    int half = id >> 9, rem = id & 511, cl = rem >> 2, pc = rem & 3;
                    *reinterpret_cast<u16x8*>(&Bt[nbuf][half][cl * 32 + pc * 8]) = sb[q];
                }
            }
            __syncthreads();
        }
    }

    // in-wave reduce over the 16 ll-lanes (xor 1,2,4,8 keeps lg fixed)
    #pragma unroll
    for (int off = 1; off < 16; off <<= 1) {
        #pragma unroll
        for (int m = 0; m < 2; ++m)
            #pragma unroll
            for (int j = 0; j < 4; ++j) {
                float ob = __shfl_xor(bv[m][j], off, 64);
                int   ok = __shfl_xor(bk[m][j], off, 64);
                float os = __shfl_xor(sv[m][j], off, 64);
                if (ob < bv[m][j] || (ob == bv[m][j] && ok < bk[m][j])) {
                    sv[m][j] = fminf(bv[m][j], os); bv[m][j] = ob; bk[m][j] = ok;
                } else {
                    sv[m][j] = fminf(sv[m][j], ob);
                }
            }
    }

    if (ll == 0) {
        #pragma unroll
        for (int m = 0; m < 2; ++m)
            #pragma unroll
            for (int j = 0; j < 4; ++j) {
                int rib = rowHalf * 32 + 16 * m + lg * 4 + j;   // C/D row map (locked)
                Lbv[codeHalf][rib] = bv[m][j];
                Lsv[codeHalf][rib] = sv[m][j];
                Lbk[codeHalf][rib] = bk[m][j];
            }
    }
    __syncthreads();

    // merge the two code-halves; half0 indices < half1 indices always
    if (tid < 64) {
        const int r = blockIdx.x * 64 + tid;
        if (r < N) {
            float b0 = Lbv[0][tid], s0 = Lsv[0][tid]; int k0 = Lbk[0][tid];
            float b1 = Lbv[1][tid], s1 = Lsv[1][tid]; int k1 = Lbk[1][tid];
            float bb, ss; int kk;
            if (b1 < b0) { bb = b1; kk = k1; ss = fminf(s1, b0); }
            else         { bb = b0; kk = k0; ss = fminf(s0, b1); }
            out[r] = kk;
            if (ss - bb <= TAU) {
                int pos = atomicAdd(count, 1);
                if (pos < LISTCAP) list[pos] = r;
            }
        }
    }
}

// ------- pass 2: exact rescore, one block per flagged row (LOCKED) -------
__global__ __launch_bounds__(256) void vq_pass2(
    const float* __restrict__ z, const float* __restrict__ emb,
    const float* __restrict__ s2g, const int* __restrict__ count,
    const int* __restrict__ list, int* __restrict__ out)
{
#pragma clang fp contract(off)
    __shared__ float zrow[DDIM];
    __shared__ float s1sh;
    __shared__ float bvw[4];
    __shared__ int   bkw[4];

    const int tid  = threadIdx.x;
    const int lane = tid & 63;
    const int wid  = tid >> 6;
    int cnt = *count; if (cnt > LISTCAP) cnt = LISTCAP;

    for (int idx = blockIdx.x; idx < cnt; idx += gridDim.x) {
        const int row = list[idx];

        if (tid < 64)
            *reinterpret_cast<float4*>(&zrow[tid * 4]) =
                *reinterpret_cast<const float4*>(z + (size_t)row * DDIM + tid * 4);
        __syncthreads();
        if (tid == 0) s1sh = block128_sq(zrow) + block128_sq(zrow + 128);
        __syncthreads();
        const float s1 = s1sh;

        float bestv = 3.4e38f;
        int   bestk = 0;
        #pragma unroll
        for (int i = 0; i < 4; ++i) {
            const int c = tid * 4 + i;
            const float* __restrict__ e = emb + (size_t)c * DDIM;
            double dot = 0.0;
            #pragma unroll 8
            for (int d4 = 0; d4 < DDIM / 4; ++d4) {
                float4 ev = *reinterpret_cast<const float4*>(e + d4 * 4);
                const float4 zv = *reinterpret_cast<const float4*>(&zrow[d4 * 4]);
                dot = fma((double)zv.x, (double)ev.x, dot);
                dot = fma((double)zv.y, (double)ev.y, dot);
                dot = fma((double)zv.z, (double)ev.z, dot);
                dot = fma((double)zv.w, (double)ev.w, dot);
            }
            float twog = 2.0f * (float)dot;
            float t1   = s1 - twog;
            float dv   = t1 + s2g[c];
            if (dv < bestv || (dv == bestv && c < bestk)) { bestv = dv; bestk = c; }
        }

        #pragma unroll
        for (int off = 1; off < 64; off <<= 1) {
            float ov = __shfl_xor(bestv, off, 64);
            int   ok = __shfl_xor(bestk, off, 64);
            if (ov < bestv || (ov == bestv && ok < bestk)) { bestv = ov; bestk = ok; }
        }
        if (lane == 0) { bvw[wid] = bestv; bkw[wid] = bestk; }
        __syncthreads();
        if (tid == 0) {
            float bb = bvw[0]; int kb = bkw[0];
            #pragma unroll
            for (int w = 1; w < 4; ++w)
                if (bvw[w] < bb || (bvw[w] == bb && bkw[w] < kb)) { bb = bvw[w]; kb = bkw[w]; }
            out[row] = kb;
        }
        __syncthreads();
    }
}

extern "C" void kernel_launch(void* const* d_in, const int* in_sizes, int n_in,
                              void* d_out, int out_size, void* d_ws, size_t ws_size,
                              hipStream_t stream) {
    const float* z   = (const float*)d_in[0];
    const float* emb = (const float*)d_in[1];
    int*   out   = (int*)d_out;
    float* s2    = (float*)d_ws;                                   // 4 KB
    int*   count = (int*)((char*)d_ws + 4096);
    int*   list  = (int*)((char*)d_ws + 4224);                     // 64 KB
    unsigned short* eh = (unsigned short*)((char*)d_ws + 131072);  // 512 KB
    const int N = in_sizes[0] / DDIM;                              // 32768

    vq_prep<<<dim3(128), dim3(256), 0, stream>>>(emb, eh, s2, count);
    vq_pass1<<<dim3(N / 64), dim3(256), 0, stream>>>(z, eh, s2, out, count, list, N);
    vq_pass2<<<dim3(4096), dim3(256), 0, stream>>>(z, emb, s2, count, list, out);
}

// Round 9
// 189.618 us; speedup vs baseline: 1.7702x; 1.7702x over previous
//
#include <hip/hip_runtime.h>

// VQ nearest-codebook argmin — bf16 MFMA pass-1 + batched exact rescore.
//
// Pass 1 (validated r8): G ≈ zh.eh, one bf16 MFMA pass; rows with top-2 gap
//   <= TAU=4e-4 get rescored.
// Pass 2 (LOCKED numerics, rounds 3-8, absmax 0): numpy-fp32 bit semantics:
//   s1,s2 pairwise fp32 sums of squares; G fp64 (any order) -> fl32(2G);
//   d = fl32(fl32(s1-2G)+s2); argmin, first-index tie-break.
//   r9 restructure: 8 rows/block, codebook tiled through LDS (transposed
//   float2 layout, conflict-free), 4-way split fp64 chains, reg-prefetch.

#define DDIM 256
#define KCODES 1024
#define TAU 4e-4f
#define LISTCAP 16384
#define ROWS2 8
#define NC2 32

typedef __attribute__((ext_vector_type(8))) short bf16x8;
typedef __attribute__((ext_vector_type(4))) float f32x4;
typedef __attribute__((ext_vector_type(8))) unsigned short u16x8;

__device__ __forceinline__ unsigned short f2bf(float f) {
    unsigned int u = __builtin_bit_cast(unsigned int, f);
    u += 0x7FFFu + ((u >> 16) & 1u);
    return (unsigned short)(u >> 16);
}

// ---------- locked numerics helper (rounds 3-8, do not touch) ----------
__device__ __forceinline__ float block128_sq(const float* __restrict__ a)
{
#pragma clang fp contract(off)
    float r[8];
    #pragma unroll
    for (int j = 0; j < 8; ++j) { float v = a[j]; r[j] = v * v; }
    #pragma unroll
    for (int i = 8; i < 128; i += 8) {
        #pragma unroll
        for (int j = 0; j < 8; ++j) { float v = a[i + j]; r[j] = r[j] + v * v; }
    }
    return ((r[0] + r[1]) + (r[2] + r[3])) + ((r[4] + r[5]) + (r[6] + r[7]));
}

// ---- prep: emb -> bf16 (eh), s2 pairwise, count reset. grid 128 x 256 ----
__global__ __launch_bounds__(256) void vq_prep(
    const float* __restrict__ emb, unsigned short* __restrict__ eh,
    float* __restrict__ s2, int* __restrict__ count)
{
    const int tid = threadIdx.x;
    if (blockIdx.x == 0 && tid == 0) *count = 0;

    const int id = blockIdx.x * 256 + tid;
    const float* src = emb + (size_t)id * 8;
    float4 p0 = *reinterpret_cast<const float4*>(src);
    float4 p1 = *reinterpret_cast<const float4*>(src + 4);
    float fv[8] = {p0.x, p0.y, p0.z, p0.w, p1.x, p1.y, p1.z, p1.w};
    u16x8 vh;
    #pragma unroll
    for (int e = 0; e < 8; ++e) vh[e] = f2bf(fv[e]);
    *reinterpret_cast<u16x8*>(eh + (size_t)id * 8) = vh;

    if (tid < 8) {
        const int c = blockIdx.x * 8 + tid;
        const float* e = emb + (size_t)c * DDIM;
        s2[c] = block128_sq(e) + block128_sq(e + 128);
    }
}

// ---------------------------- pass 1 (bf16 MFMA, r8-validated) ----------------------------
__global__ __launch_bounds__(256, 2) void vq_pass1(
    const float* __restrict__ z, const unsigned short* __restrict__ eh,
    const float* __restrict__ s2g, int* __restrict__ out,
    int* __restrict__ count, int* __restrict__ list, int N)
{
    __shared__ __align__(16) unsigned short Bt[2][2][4096];
    __shared__ float s2s[KCODES];
    __shared__ float Lbv[2][64], Lsv[2][64];
    __shared__ int   Lbk[2][64];

    const int tid  = threadIdx.x;
    const int wid  = tid >> 6, lane = tid & 63;
    const int ll   = lane & 15, lg = lane >> 4;
    const int rowHalf  = wid & 1, codeHalf = wid >> 1;
    const int rowbase  = blockIdx.x * 64 + rowHalf * 32;
    const int chbase   = codeHalf * 512;

    for (int c = tid; c < KCODES; c += 256) s2s[c] = s2g[c];

    const int sB     = (ll >> 1) & 3;
    const int rdbase = ll * 32 + ((lg ^ sB) << 3);

    bf16x8 afrag[8][2];
    f32x4  acc[2][8];
    float  bv[2][4], sv[2][4];
    int    bk[2][4];
    #pragma unroll
    for (int m = 0; m < 2; ++m)
        #pragma unroll
        for (int j = 0; j < 4; ++j) { bv[m][j] = 3.4e38f; sv[m][j] = 3.4e38f; bk[m][j] = 0; }

    {
        #pragma unroll
        for (int q = 0; q < 4; ++q) {
            int id = q * 256 + tid;
            int half = id >> 9, rem = id & 511, cl = rem >> 2, pc = rem & 3;
            int clog = pc ^ ((cl >> 1) & 3);
            u16x8 v = *reinterpret_cast<const u16x8*>(
                eh + (size_t)(half * 512 + cl) * DDIM + clog * 8);
            *reinterpret_cast<u16x8*>(&Bt[0][half][cl * 32 + pc * 8]) = v;
        }
    }
    __syncthreads();

    for (int ct = 0; ct < 4; ++ct) {
        const f32x4 zero4 = {0.f, 0.f, 0.f, 0.f};
        #pragma unroll
        for (int m = 0; m < 2; ++m)
            #pragma unroll
            for (int n = 0; n < 8; ++n) acc[m][n] = zero4;

        #pragma unroll
        for (int ks = 0; ks < 8; ++ks) {
            const int buf = ks & 1;
            const int t   = ct * 8 + ks;
            const bool hasNext = (t < 31);

            u16x8 sb[4];
            if (hasNext) {
                const int nt = t + 1, nct = nt >> 3, nks = nt & 7;
                #pragma unroll
                for (int q = 0; q < 4; ++q) {
                    int id = q * 256 + tid;
                    int half = id >> 9, rem = id & 511, cl = rem >> 2, pc = rem & 3;
                    int clog = pc ^ ((cl >> 1) & 3);
                    sb[q] = *reinterpret_cast<const u16x8*>(
                        eh + (size_t)(half * 512 + nct * 128 + cl) * DDIM + nks * 32 + clog * 8);
                }
            }

            if (ct == 0) {
                #pragma unroll
                for (int m = 0; m < 2; ++m) {
                    const float* zp = z + (size_t)(rowbase + 16 * m + ll) * DDIM + ks * 32 + lg * 8;
                    float4 p0 = *reinterpret_cast<const float4*>(zp);
                    float4 p1 = *reinterpret_cast<const float4*>(zp + 4);
                    float fv[8] = {p0.x, p0.y, p0.z, p0.w, p1.x, p1.y, p1.z, p1.w};
                    #pragma unroll
                    for (int e = 0; e < 8; ++e) afrag[ks][m][e] = (short)f2bf(fv[e]);
                }
            }

            #pragma unroll
            for (int n = 0; n < 8; ++n) {
                bf16x8 bh = *reinterpret_cast<const bf16x8*>(
                    &Bt[buf][codeHalf][n * 512 + rdbase]);
                #pragma unroll
                for (int m = 0; m < 2; ++m)
                    acc[m][n] = __builtin_amdgcn_mfma_f32_16x16x32_bf16(
                        afrag[ks][m], bh, acc[m][n], 0, 0, 0);
            }

            if (ks == 7) {
                #pragma unroll
                for (int n = 0; n < 8; ++n) {
                    const int c = chbase + ct * 128 + n * 16 + ll;
                    const float s2v = s2s[c];
                    #pragma unroll
                    for (int m = 0; m < 2; ++m)
                        #pragma unroll
                        for (int j = 0; j < 4; ++j) {
                            float v = fmaf(-2.0f, acc[m][n][j], s2v);
                            if (v < bv[m][j] || (v == bv[m][j] && c < bk[m][j])) {
                                sv[m][j] = bv[m][j]; bv[m][j] = v; bk[m][j] = c;
                            } else {
                                sv[m][j] = fminf(sv[m][j], v);
                            }
                        }
                }
            }

            if (hasNext) {
                const int nbuf = buf ^ 1;
                #pragma unroll
                for (int q = 0; q < 4; ++q) {
                    int id = q * 256 + tid;
                    int half = id >> 9, rem = id & 511, cl = rem >> 2, pc = rem & 3;
                    *reinterpret_cast<u16x8*>(&Bt[nbuf][half][cl * 32 + pc * 8]) = sb[q];
                }
            }
            __syncthreads();
        }
    }

    #pragma unroll
    for (int off = 1; off < 16; off <<= 1) {
        #pragma unroll
        for (int m = 0; m < 2; ++m)
            #pragma unroll
            for (int j = 0; j < 4; ++j) {
                float ob = __shfl_xor(bv[m][j], off, 64);
                int   ok = __shfl_xor(bk[m][j], off, 64);
                float os = __shfl_xor(sv[m][j], off, 64);
                if (ob < bv[m][j] || (ob == bv[m][j] && ok < bk[m][j])) {
                    sv[m][j] = fminf(bv[m][j], os); bv[m][j] = ob; bk[m][j] = ok;
                } else {
                    sv[m][j] = fminf(sv[m][j], ob);
                }
            }
    }

    if (ll == 0) {
        #pragma unroll
        for (int m = 0; m < 2; ++m)
            #pragma unroll
            for (int j = 0; j < 4; ++j) {
                int rib = rowHalf * 32 + 16 * m + lg * 4 + j;
                Lbv[codeHalf][rib] = bv[m][j];
                Lsv[codeHalf][rib] = sv[m][j];
                Lbk[codeHalf][rib] = bk[m][j];
            }
    }
    __syncthreads();

    if (tid < 64) {
        const int r = blockIdx.x * 64 + tid;
        if (r < N) {
            float b0 = Lbv[0][tid], s0 = Lsv[0][tid]; int k0 = Lbk[0][tid];
            float b1 = Lbv[1][tid], s1 = Lsv[1][tid]; int k1 = Lbk[1][tid];
            float bb, ss; int kk;
            if (b1 < b0) { bb = b1; kk = k1; ss = fminf(s1, b0); }
            else         { bb = b0; kk = k0; ss = fminf(s0, b1); }
            out[r] = kk;
            if (ss - bb <= TAU) {
                int pos = atomicAdd(count, 1);
                if (pos < LISTCAP) list[pos] = r;
            }
        }
    }
}

// ------- pass 2: exact rescore, 8 rows/block, LDS-tiled codebook (LOCKED numerics) -------
__global__ __launch_bounds__(256) void vq_pass2(
    const float* __restrict__ z, const float* __restrict__ emb,
    const float* __restrict__ s2g, const int* __restrict__ count,
    const int* __restrict__ list, int* __restrict__ out)
{
#pragma clang fp contract(off)
    __shared__ float  Zs[ROWS2][DDIM];     //  8 KB
    __shared__ float2 Et[128][33];         // 33.8 KB, [j2][code] transposed+pad
    __shared__ float  s1s[ROWS2];
    __shared__ float  s2s[KCODES];         //  4 KB
    __shared__ int    rowids[ROWS2];

    const int tid = threadIdx.x;
    int cnt = *count; if (cnt > LISTCAP) cnt = LISTCAP;
    const int ngroups = (cnt + ROWS2 - 1) / ROWS2;

    for (int c = tid; c < KCODES; c += 256) s2s[c] = s2g[c];

    const int r  = tid >> 5;         // 0..7  (row within group)
    const int cc = tid & 31;         // code class
    const int scode = tid >> 3;      // staging: code 0..31
    const int schnk = tid & 7;       // staging: chunk 0..7

    for (int g = blockIdx.x; g < ngroups; g += gridDim.x) {
        if (tid < ROWS2) {
            int i = g * ROWS2 + tid;
            rowids[tid] = list[i < cnt ? i : (cnt - 1)];
        }
        __syncthreads();                               // rowids visible

        #pragma unroll
        for (int it = 0; it < 2; ++it) {               // stage 8 z rows
            int f4 = it * 256 + tid;
            int rr = f4 >> 6, c4 = f4 & 63;
            *reinterpret_cast<float4*>(&Zs[rr][c4 * 4]) =
                *reinterpret_cast<const float4*>(z + (size_t)rowids[rr] * DDIM + c4 * 4);
        }

        float4 rb[8];                                  // tile-0 codebook prefetch
        #pragma unroll
        for (int q = 0; q < 8; ++q)
            rb[q] = *reinterpret_cast<const float4*>(
                emb + (size_t)scode * DDIM + (schnk + 8 * q) * 4);

        __syncthreads();                               // Zs complete
        if (tid < ROWS2)                               // locked pairwise s1
            s1s[tid] = block128_sq(&Zs[tid][0]) + block128_sq(&Zs[tid][128]);

        float bestv = 3.4e38f;
        int   bestk = 0;

        for (int t = 0; t < KCODES / NC2; ++t) {
            #pragma unroll
            for (int q = 0; q < 8; ++q) {              // write tile t
                int ch = schnk + 8 * q;
                Et[2 * ch][scode]     = make_float2(rb[q].x, rb[q].y);
                Et[2 * ch + 1][scode] = make_float2(rb[q].z, rb[q].w);
            }
            if (t + 1 < KCODES / NC2) {                // prefetch tile t+1
                #pragma unroll
                for (int q = 0; q < 8; ++q)
                    rb[q] = *reinterpret_cast<const float4*>(
                        emb + (size_t)((t + 1) * NC2 + scode) * DDIM + (schnk + 8 * q) * 4);
            }
            __syncthreads();                           // Et ready (and s1s at t==0)

            double d0 = 0.0, d1 = 0.0, d2 = 0.0, d3 = 0.0;
            const float2* zp2 = reinterpret_cast<const float2*>(&Zs[r][0]);
            #pragma unroll
            for (int i = 0; i < 32; ++i) {
                float2 e0 = Et[4 * i + 0][cc], e1 = Et[4 * i + 1][cc];
                float2 e2 = Et[4 * i + 2][cc], e3 = Et[4 * i + 3][cc];
                float2 z0 = zp2[4 * i + 0], z1 = zp2[4 * i + 1];
                float2 z2 = zp2[4 * i + 2], z3 = zp2[4 * i + 3];
                d0 = fma((double)z0.x, (double)e0.x, d0); d0 = fma((double)z0.y, (double)e0.y, d0);
                d1 = fma((double)z1.x, (double)e1.x, d1); d1 = fma((double)z1.y, (double)e1.y, d1);
                d2 = fma((double)z2.x, (double)e2.x, d2); d2 = fma((double)z2.y, (double)e2.y, d2);
                d3 = fma((double)z3.x, (double)e3.x, d3); d3 = fma((double)z3.y, (double)e3.y, d3);
            }
            double dot = (d0 + d1) + (d2 + d3);        // fp64 order-free
            const int c = t * NC2 + cc;
            float twog = 2.0f * (float)dot;            // LOCKED: fl32(2G)
            float t1v  = s1s[r] - twog;                // fp32 rounding 1
            float dv   = t1v + s2s[c];                 // fp32 rounding 2
            if (dv < bestv || (dv == bestv && c < bestk)) { bestv = dv; bestk = c; }
            __syncthreads();                           // before Et overwrite
        }

        // reduce across the 32 code-class lanes (xor 1..16 keeps r fixed)
        #pragma unroll
        for (int off = 1; off < 32; off <<= 1) {
            float ov = __shfl_xor(bestv, off, 64);
            int   ok = __shfl_xor(bestk, off, 64);
            if (ov < bestv || (ov == bestv && ok < bestk)) { bestv = ov; bestk = ok; }
        }
        if (cc == 0) out[rowids[r]] = bestk;
        __syncthreads();                               // protect rowids/Zs/s1s
    }
}

extern "C" void kernel_launch(void* const* d_in, const int* in_sizes, int n_in,
                              void* d_out, int out_size, void* d_ws, size_t ws_size,
                              hipStream_t stream) {
    const float* z   = (const float*)d_in[0];
    const float* emb = (const float*)d_in[1];
    int*   out   = (int*)d_out;
    float* s2    = (float*)d_ws;                                   // 4 KB
    int*   count = (int*)((char*)d_ws + 4096);
    int*   list  = (int*)((char*)d_ws + 4224);                     // 64 KB
    unsigned short* eh = (unsigned short*)((char*)d_ws + 131072);  // 512 KB
    const int N = in_sizes[0] / DDIM;                              // 32768

    vq_prep<<<dim3(128), dim3(256), 0, stream>>>(emb, eh, s2, count);
    vq_pass1<<<dim3(N / 64), dim3(256), 0, stream>>>(z, eh, s2, out, count, list, N);
    vq_pass2<<<dim3(512), dim3(256), 0, stream>>>(z, emb, s2, count, list, out);
}

// Round 10
// 141.571 us; speedup vs baseline: 2.3710x; 1.3394x over previous
//
#include <hip/hip_runtime.h>

// VQ nearest-codebook argmin — fp16 MFMA pass-1 + fp32-scan/exact-window rescore.
//
// Pass 1: G ≈ z16 . fp16(1024 e) / 1024, one f16 MFMA pass (noise 2G sigma ~1e-5).
//   Rows with top-2 gap <= TAU=1.6e-4 (ref slack 6.4e-5 + 7 sigma) -> list.
// Pass 2: per flagged row, fp32 scan of all 1024 v = s2 - 2 z.e (err <= 3e-7),
//   then LOCKED numpy-fp32 recipe (rounds 3-9, absmax 0) only for codes with
//   v <= bv + WIN=1e-4 (covers 2x(np rounding 3.4e-5) -> non-candidates can
//   neither win nor tie). Recipe: s1,s2 numpy-pairwise fp32 sums of squares;
//   G exact-fp64 (order-free) -> fl32(2G); d = fl32(fl32(s1-2G)+s2);
//   argmin, first-index tie-break.

#define DDIM 256
#define KCODES 1024
#define TAU 1.6e-4f
#define WIN 1.0e-4f
#define LISTCAP 16384
#define ROWS2 8
#define NC2 32
#define CANDCAP 128

typedef __attribute__((ext_vector_type(8))) _Float16 f16x8;
typedef __attribute__((ext_vector_type(4))) float f32x4;
typedef __attribute__((ext_vector_type(8))) unsigned short u16x8;

// ---------- locked numerics helper (rounds 3-9, do not touch) ----------
__device__ __forceinline__ float block128_sq(const float* __restrict__ a)
{
#pragma clang fp contract(off)
    float r[8];
    #pragma unroll
    for (int j = 0; j < 8; ++j) { float v = a[j]; r[j] = v * v; }
    #pragma unroll
    for (int i = 8; i < 128; i += 8) {
        #pragma unroll
        for (int j = 0; j < 8; ++j) { float v = a[i + j]; r[j] = r[j] + v * v; }
    }
    return ((r[0] + r[1]) + (r[2] + r[3])) + ((r[4] + r[5]) + (r[6] + r[7]));
}

// ---- prep: e16 = fp16(1024*e), s2 pairwise, count reset. grid 128 x 256 ----
__global__ __launch_bounds__(256) void vq_prep(
    const float* __restrict__ emb, unsigned short* __restrict__ e16,
    float* __restrict__ s2, int* __restrict__ count)
{
    const int tid = threadIdx.x;
    if (blockIdx.x == 0 && tid == 0) *count = 0;

    const int id = blockIdx.x * 256 + tid;            // ushort8 chunk, 32768 total
    const float* src = emb + (size_t)id * 8;
    float4 p0 = *reinterpret_cast<const float4*>(src);
    float4 p1 = *reinterpret_cast<const float4*>(src + 4);
    float fv[8] = {p0.x, p0.y, p0.z, p0.w, p1.x, p1.y, p1.z, p1.w};
    u16x8 vh;
    #pragma unroll
    for (int e = 0; e < 8; ++e) {
        _Float16 h = (_Float16)(fv[e] * 1024.0f);     // pow2 scale exact; RNE cvt
        vh[e] = __builtin_bit_cast(unsigned short, h);
    }
    *reinterpret_cast<u16x8*>(e16 + (size_t)id * 8) = vh;

    if (tid < 8) {
        const int c = blockIdx.x * 8 + tid;
        const float* e = emb + (size_t)c * DDIM;
        s2[c] = block128_sq(e) + block128_sq(e + 128);
    }
}

// ---------------------------- pass 1 (fp16 MFMA) ----------------------------
// r8/r9-validated structure; dtype bf16 -> fp16(1024e), fold scale 2^-9.
__global__ __launch_bounds__(256, 2) void vq_pass1(
    const float* __restrict__ z, const unsigned short* __restrict__ e16,
    const float* __restrict__ s2g, int* __restrict__ out,
    int* __restrict__ count, int* __restrict__ list, int N)
{
    __shared__ __align__(16) unsigned short Bt[2][2][4096];
    __shared__ float s2s[KCODES];
    __shared__ float Lbv[2][64], Lsv[2][64];
    __shared__ int   Lbk[2][64];

    const int tid  = threadIdx.x;
    const int wid  = tid >> 6, lane = tid & 63;
    const int ll   = lane & 15, lg = lane >> 4;
    const int rowHalf  = wid & 1, codeHalf = wid >> 1;
    const int rowbase  = blockIdx.x * 64 + rowHalf * 32;
    const int chbase   = codeHalf * 512;

    for (int c = tid; c < KCODES; c += 256) s2s[c] = s2g[c];

    const int sB     = (ll >> 1) & 3;
    const int rdbase = ll * 32 + ((lg ^ sB) << 3);

    f16x8  afrag[8][2];
    f32x4  acc[2][8];
    float  bv[2][4], sv[2][4];
    int    bk[2][4];
    #pragma unroll
    for (int m = 0; m < 2; ++m)
        #pragma unroll
        for (int j = 0; j < 4; ++j) { bv[m][j] = 3.4e38f; sv[m][j] = 3.4e38f; bk[m][j] = 0; }

    {
        #pragma unroll
        for (int q = 0; q < 4; ++q) {
            int id = q * 256 + tid;
            int half = id >> 9, rem = id & 511, cl = rem >> 2, pc = rem & 3;
            int clog = pc ^ ((cl >> 1) & 3);
            u16x8 v = *reinterpret_cast<const u16x8*>(
                e16 + (size_t)(half * 512 + cl) * DDIM + clog * 8);
            *reinterpret_cast<u16x8*>(&Bt[0][half][cl * 32 + pc * 8]) = v;
        }
    }
    __syncthreads();

    for (int ct = 0; ct < 4; ++ct) {
        const f32x4 zero4 = {0.f, 0.f, 0.f, 0.f};
        #pragma unroll
        for (int m = 0; m < 2; ++m)
            #pragma unroll
            for (int n = 0; n < 8; ++n) acc[m][n] = zero4;

        #pragma unroll
        for (int ks = 0; ks < 8; ++ks) {
            const int buf = ks & 1;
            const int t   = ct * 8 + ks;
            const bool hasNext = (t < 31);

            u16x8 sb[4];
            if (hasNext) {
                const int nt = t + 1, nct = nt >> 3, nks = nt & 7;
                #pragma unroll
                for (int q = 0; q < 4; ++q) {
                    int id = q * 256 + tid;
                    int half = id >> 9, rem = id & 511, cl = rem >> 2, pc = rem & 3;
                    int clog = pc ^ ((cl >> 1) & 3);
                    sb[q] = *reinterpret_cast<const u16x8*>(
                        e16 + (size_t)(half * 512 + nct * 128 + cl) * DDIM + nks * 32 + clog * 8);
                }
            }

            if (ct == 0) {      // convert A rows to fp16 once, reuse ct=1..3
                #pragma unroll
                for (int m = 0; m < 2; ++m) {
                    const float* zp = z + (size_t)(rowbase + 16 * m + ll) * DDIM + ks * 32 + lg * 8;
                    float4 p0 = *reinterpret_cast<const float4*>(zp);
                    float4 p1 = *reinterpret_cast<const float4*>(zp + 4);
                    float fv[8] = {p0.x, p0.y, p0.z, p0.w, p1.x, p1.y, p1.z, p1.w};
                    #pragma unroll
                    for (int e = 0; e < 8; ++e) afrag[ks][m][e] = (_Float16)fv[e];
                }
            }

            #pragma unroll
            for (int n = 0; n < 8; ++n) {
                f16x8 bh = *reinterpret_cast<const f16x8*>(
                    &Bt[buf][codeHalf][n * 512 + rdbase]);
                #pragma unroll
                for (int m = 0; m < 2; ++m)
                    acc[m][n] = __builtin_amdgcn_mfma_f32_16x16x32_f16(
                        afrag[ks][m], bh, acc[m][n], 0, 0, 0);
            }

            if (ks == 7) {      // fold: v = s2 - 2^-9 * dot'
                #pragma unroll
                for (int n = 0; n < 8; ++n) {
                    const int c = chbase + ct * 128 + n * 16 + ll;
                    const float s2v = s2s[c];
                    #pragma unroll
                    for (int m = 0; m < 2; ++m)
                        #pragma unroll
                        for (int j = 0; j < 4; ++j) {
                            float v = fmaf(-0.001953125f, acc[m][n][j], s2v);
                            if (v < bv[m][j] || (v == bv[m][j] && c < bk[m][j])) {
                                sv[m][j] = bv[m][j]; bv[m][j] = v; bk[m][j] = c;
                            } else {
                                sv[m][j] = fminf(sv[m][j], v);
                            }
                        }
                }
            }

            if (hasNext) {
                const int nbuf = buf ^ 1;
                #pragma unroll
                for (int q = 0; q < 4; ++q) {
                    int id = q * 256 + tid;
                    int half = id >> 9, rem = id & 511, cl = rem >> 2, pc = rem & 3;
                    *reinterpret_cast<u16x8*>(&Bt[nbuf][half][cl * 32 + pc * 8]) = sb[q];
                }
            }
            __syncthreads();
        }
    }

    #pragma unroll
    for (int off = 1; off < 16; off <<= 1) {
        #pragma unroll
        for (int m = 0; m < 2; ++m)
            #pragma unroll
            for (int j = 0; j < 4; ++j) {
                float ob = __shfl_xor(bv[m][j], off, 64);
                int   ok = __shfl_xor(bk[m][j], off, 64);
                float os = __shfl_xor(sv[m][j], off, 64);
                if (ob < bv[m][j] || (ob == bv[m][j] && ok < bk[m][j])) {
                    sv[m][j] = fminf(bv[m][j], os); bv[m][j] = ob; bk[m][j] = ok;
                } else {
                    sv[m][j] = fminf(sv[m][j], ob);
                }
            }
    }

    if (ll == 0) {
        #pragma unroll
        for (int m = 0; m < 2; ++m)
            #pragma unroll
            for (int j = 0; j < 4; ++j) {
                int rib = rowHalf * 32 + 16 * m + lg * 4 + j;
                Lbv[codeHalf][rib] = bv[m][j];
                Lsv[codeHalf][rib] = sv[m][j];
                Lbk[codeHalf][rib] = bk[m][j];
            }
    }
    __syncthreads();

    if (tid < 64) {
        const int r = blockIdx.x * 64 + tid;
        if (r < N) {
            float b0 = Lbv[0][tid], s0 = Lsv[0][tid]; int k0 = Lbk[0][tid];
            float b1 = Lbv[1][tid], s1 = Lsv[1][tid]; int k1 = Lbk[1][tid];
            float bb, ss; int kk;
            if (b1 < b0) { bb = b1; kk = k1; ss = fminf(s1, b0); }
            else         { bb = b0; kk = k0; ss = fminf(s0, b1); }
            out[r] = kk;
            if (ss - bb <= TAU) {
                int pos = atomicAdd(count, 1);
                if (pos < LISTCAP) list[pos] = r;
            }
        }
    }
}

// ------- pass 2: fp32 scan + exact window (LOCKED recipe), 8 rows/block -------
__global__ __launch_bounds__(256) void vq_pass2(
    const float* __restrict__ z, const float* __restrict__ emb,
    const float* __restrict__ s2g, const int* __restrict__ count,
    const int* __restrict__ list, int* __restrict__ out)
{
#pragma clang fp contract(off)
    __shared__ float  Zs[ROWS2][DDIM];     //  8 KB
    __shared__ float2 Et[128][33];         // 33.8 KB
    __shared__ float  Vs[ROWS2][KCODES];   // 32 KB (bank = cc, conflict-free)
    __shared__ float  s1s[ROWS2];
    __shared__ float  s2s[KCODES];         //  4 KB
    __shared__ float  bvs[ROWS2];
    __shared__ int    rowids[ROWS2];
    __shared__ int    nc;
    __shared__ int    cand_c[CANDCAP], cand_r[CANDCAP];
    __shared__ float  cand_v[CANDCAP];

    const int tid = threadIdx.x;
    int cnt = *count; if (cnt > LISTCAP) cnt = LISTCAP;
    if (cnt == 0) return;
    const int ngroups = (cnt + ROWS2 - 1) / ROWS2;

    for (int c = tid; c < KCODES; c += 256) s2s[c] = s2g[c];

    const int r    = tid >> 5;       // row in group
    const int cc   = tid & 31;       // code class
    const int lane = tid & 63, wid = tid >> 6;
    const int scode = tid >> 3, schnk = tid & 7;

    for (int g = blockIdx.x; g < ngroups; g += gridDim.x) {
        if (tid < ROWS2) {
            int i = g * ROWS2 + tid;
            rowids[tid] = list[i < cnt ? i : (cnt - 1)];
        }
        if (tid == 0) nc = 0;
        __syncthreads();

        #pragma unroll
        for (int it = 0; it < 2; ++it) {               // stage 8 z rows
            int f4 = it * 256 + tid;
            int rr = f4 >> 6, c4 = f4 & 63;
            *reinterpret_cast<float4*>(&Zs[rr][c4 * 4]) =
                *reinterpret_cast<const float4*>(z + (size_t)rowids[rr] * DDIM + c4 * 4);
        }

        float4 rb[8];                                  // tile-0 prefetch
        #pragma unroll
        for (int q = 0; q < 8; ++q)
            rb[q] = *reinterpret_cast<const float4*>(
                emb + (size_t)scode * DDIM + (schnk + 8 * q) * 4);

        __syncthreads();
        if (tid < ROWS2)                               // LOCKED pairwise s1
            s1s[tid] = block128_sq(&Zs[tid][0]) + block128_sq(&Zs[tid][128]);

        float bestv = 3.4e38f;

        for (int t = 0; t < KCODES / NC2; ++t) {       // ---- fp32 scan ----
            #pragma unroll
            for (int q = 0; q < 8; ++q) {
                int ch = schnk + 8 * q;
                Et[2 * ch][scode]     = make_float2(rb[q].x, rb[q].y);
                Et[2 * ch + 1][scode] = make_float2(rb[q].z, rb[q].w);
            }
            if (t + 1 < KCODES / NC2) {
                #pragma unroll
                for (int q = 0; q < 8; ++q)
                    rb[q] = *reinterpret_cast<const float4*>(
                        emb + (size_t)((t + 1) * NC2 + scode) * DDIM + (schnk + 8 * q) * 4);
            }
            __syncthreads();

            float d0 = 0.f, d1 = 0.f, d2 = 0.f, d3 = 0.f;
            const float2* zp2 = reinterpret_cast<const float2*>(&Zs[r][0]);
            #pragma unroll
            for (int i = 0; i < 32; ++i) {
                float2 e0 = Et[4 * i + 0][cc], e1 = Et[4 * i + 1][cc];
                float2 e2 = Et[4 * i + 2][cc], e3 = Et[4 * i + 3][cc];
                float2 z0 = zp2[4 * i + 0], z1 = zp2[4 * i + 1];
                float2 z2 = zp2[4 * i + 2], z3 = zp2[4 * i + 3];
                d0 = fmaf(z0.x, e0.x, d0); d0 = fmaf(z0.y, e0.y, d0);
                d1 = fmaf(z1.x, e1.x, d1); d1 = fmaf(z1.y, e1.y, d1);
                d2 = fmaf(z2.x, e2.x, d2); d2 = fmaf(z2.y, e2.y, d2);
                d3 = fmaf(z3.x, e3.x, d3); d3 = fmaf(z3.y, e3.y, d3);
            }
            float dotf = (d0 + d1) + (d2 + d3);        // scan err <= ~3e-7
            float v = fmaf(-2.0f, dotf, s2s[t * NC2 + cc]);
            Vs[r][t * NC2 + cc] = v;
            bestv = fminf(bestv, v);
            __syncthreads();
        }

        #pragma unroll
        for (int off = 1; off < 32; off <<= 1)         // row-best over cc lanes
            bestv = fminf(bestv, __shfl_xor(bestv, off, 64));
        if (cc == 0) bvs[r] = bestv;
        __syncthreads();

        const float bvr = bvs[r];                      // ---- candidates ----
        for (int t = 0; t < KCODES / NC2; ++t) {
            float v = Vs[r][t * NC2 + cc];
            if (v <= bvr + WIN) {
                int p = atomicAdd(&nc, 1);
                if (p < CANDCAP) { cand_c[p] = t * NC2 + cc; cand_r[p] = r; }
            }
        }
        __syncthreads();
        int tot = nc; if (tot > CANDCAP) tot = CANDCAP;

        // ---- exact eval per candidate, one wave each (LOCKED recipe) ----
        for (int i = wid; i < tot; i += 4) {
            const int c = cand_c[i], rr = cand_r[i];
            float4 ev = *reinterpret_cast<const float4*>(emb + (size_t)c * DDIM + lane * 4);
            const float* zp = &Zs[rr][lane * 4];
            double dsum = (double)zp[0] * (double)ev.x;
            dsum = fma((double)zp[1], (double)ev.y, dsum);
            dsum = fma((double)zp[2], (double)ev.z, dsum);
            dsum = fma((double)zp[3], (double)ev.w, dsum);
            #pragma unroll
            for (int off = 1; off < 64; off <<= 1)
                dsum += __shfl_xor(dsum, off, 64);     // fp64 order-free exact
            if (lane == 0) {
                float twog = 2.0f * (float)dsum;       // LOCKED: fl32(2G)
                float t1   = s1s[rr] - twog;           // fp32 rounding 1
                cand_v[i]  = t1 + s2s[c];              // fp32 rounding 2
            }
        }
        __syncthreads();

        if (tid < ROWS2) {                             // first-index argmin
            float bb = 3.4e38f; int bkk = KCODES;
            for (int i = 0; i < tot; ++i)
                if (cand_r[i] == tid) {
                    float dv = cand_v[i]; int c = cand_c[i];
                    if (dv < bb || (dv == bb && c < bkk)) { bb = dv; bkk = c; }
                }
            out[rowids[tid]] = bkk;
        }
        __syncthreads();
    }
}

extern "C" void kernel_launch(void* const* d_in, const int* in_sizes, int n_in,
                              void* d_out, int out_size, void* d_ws, size_t ws_size,
                              hipStream_t stream) {
    const float* z   = (const float*)d_in[0];
    const float* emb = (const float*)d_in[1];
    int*   out   = (int*)d_out;
    float* s2    = (float*)d_ws;                                   // 4 KB
    int*   count = (int*)((char*)d_ws + 4096);
    int*   list  = (int*)((char*)d_ws + 4224);                     // 64 KB
    unsigned short* e16 = (unsigned short*)((char*)d_ws + 131072); // 512 KB
    const int N = in_sizes[0] / DDIM;                              // 32768

    vq_prep<<<dim3(128), dim3(256), 0, stream>>>(emb, e16, s2, count);
    vq_pass1<<<dim3(N / 64), dim3(256), 0, stream>>>(z, e16, s2, out, count, list, N);
    vq_pass2<<<dim3(512), dim3(256), 0, stream>>>(z, emb, s2, count, list, out);
}

// Round 11
// 136.702 us; speedup vs baseline: 2.4554x; 1.0356x over previous
//
#include <hip/hip_runtime.h>

// VQ nearest-codebook argmin — fp16 MFMA pass-1 + wave-per-row rescore.
//
// Pass 1 (validated r8-r10): G ≈ z16 . fp16(1024 e) / 1024, one f16 MFMA pass.
//   Rows with top-2 gap <= TAU=1.6e-4 -> list.
// Pass 2: ONE WAVE PER flagged row. fp16 dot2 scan of all 1024 codes
//   (error sigma ~4.5e-6), candidates = v <= bv + WIN=1.2e-4 (np-slack 6.1e-5
//   + 13 sigma). Then LOCKED numpy-fp32 recipe (rounds 3-10, absmax 0) per
//   candidate: s1,s2 numpy-pairwise fp32 sums of squares; G exact-fp64
//   (order-free) -> fl32(2G); d = fl32(fl32(s1-2G)+s2); argmin,
//   first-index tie-break.

#define DDIM 256
#define KCODES 1024
#define TAU 1.6e-4f
#define WIN 1.2e-4f
#define LISTCAP 16384
#define CANDCAP 16

typedef __attribute__((ext_vector_type(8))) _Float16 f16x8;
typedef __attribute__((ext_vector_type(2))) _Float16 h2;
typedef __attribute__((ext_vector_type(4))) float f32x4;
typedef __attribute__((ext_vector_type(8))) unsigned short u16x8;

// ---------- locked numerics helper (rounds 3-10, do not touch) ----------
__device__ __forceinline__ float block128_sq(const float* __restrict__ a)
{
#pragma clang fp contract(off)
    float r[8];
    #pragma unroll
    for (int j = 0; j < 8; ++j) { float v = a[j]; r[j] = v * v; }
    #pragma unroll
    for (int i = 8; i < 128; i += 8) {
        #pragma unroll
        for (int j = 0; j < 8; ++j) { float v = a[i + j]; r[j] = r[j] + v * v; }
    }
    return ((r[0] + r[1]) + (r[2] + r[3])) + ((r[4] + r[5]) + (r[6] + r[7]));
}

// ---- prep: e16 = fp16(1024*e), s2 pairwise, count reset (r9-validated) ----
__global__ __launch_bounds__(256) void vq_prep(
    const float* __restrict__ emb, unsigned short* __restrict__ e16,
    float* __restrict__ s2, int* __restrict__ count)
{
    const int tid = threadIdx.x;
    if (blockIdx.x == 0 && tid == 0) *count = 0;

    const int id = blockIdx.x * 256 + tid;
    const float* src = emb + (size_t)id * 8;
    float4 p0 = *reinterpret_cast<const float4*>(src);
    float4 p1 = *reinterpret_cast<const float4*>(src + 4);
    float fv[8] = {p0.x, p0.y, p0.z, p0.w, p1.x, p1.y, p1.z, p1.w};
    u16x8 vh;
    #pragma unroll
    for (int e = 0; e < 8; ++e) {
        _Float16 h = (_Float16)(fv[e] * 1024.0f);
        vh[e] = __builtin_bit_cast(unsigned short, h);
    }
    *reinterpret_cast<u16x8*>(e16 + (size_t)id * 8) = vh;

    if (tid < 8) {
        const int c = blockIdx.x * 8 + tid;
        const float* e = emb + (size_t)c * DDIM;
        s2[c] = block128_sq(e) + block128_sq(e + 128);
    }
}

// ---------------------------- pass 1 (fp16 MFMA, r10 verbatim) ----------------------------
__global__ __launch_bounds__(256, 2) void vq_pass1(
    const float* __restrict__ z, const unsigned short* __restrict__ e16,
    const float* __restrict__ s2g, int* __restrict__ out,
    int* __restrict__ count, int* __restrict__ list, int N)
{
    __shared__ __align__(16) unsigned short Bt[2][2][4096];
    __shared__ float s2s[KCODES];
    __shared__ float Lbv[2][64], Lsv[2][64];
    __shared__ int   Lbk[2][64];

    const int tid  = threadIdx.x;
    const int wid  = tid >> 6, lane = tid & 63;
    const int ll   = lane & 15, lg = lane >> 4;
    const int rowHalf  = wid & 1, codeHalf = wid >> 1;
    const int rowbase  = blockIdx.x * 64 + rowHalf * 32;
    const int chbase   = codeHalf * 512;

    for (int c = tid; c < KCODES; c += 256) s2s[c] = s2g[c];

    const int sB     = (ll >> 1) & 3;
    const int rdbase = ll * 32 + ((lg ^ sB) << 3);

    f16x8  afrag[8][2];
    f32x4  acc[2][8];
    float  bv[2][4], sv[2][4];
    int    bk[2][4];
    #pragma unroll
    for (int m = 0; m < 2; ++m)
        #pragma unroll
        for (int j = 0; j < 4; ++j) { bv[m][j] = 3.4e38f; sv[m][j] = 3.4e38f; bk[m][j] = 0; }

    {
        #pragma unroll
        for (int q = 0; q < 4; ++q) {
            int id = q * 256 + tid;
            int half = id >> 9, rem = id & 511, cl = rem >> 2, pc = rem & 3;
            int clog = pc ^ ((cl >> 1) & 3);
            u16x8 v = *reinterpret_cast<const u16x8*>(
                e16 + (size_t)(half * 512 + cl) * DDIM + clog * 8);
            *reinterpret_cast<u16x8*>(&Bt[0][half][cl * 32 + pc * 8]) = v;
        }
    }
    __syncthreads();

    for (int ct = 0; ct < 4; ++ct) {
        const f32x4 zero4 = {0.f, 0.f, 0.f, 0.f};
        #pragma unroll
        for (int m = 0; m < 2; ++m)
            #pragma unroll
            for (int n = 0; n < 8; ++n) acc[m][n] = zero4;

        #pragma unroll
        for (int ks = 0; ks < 8; ++ks) {
            const int buf = ks & 1;
            const int t   = ct * 8 + ks;
            const bool hasNext = (t < 31);

            u16x8 sb[4];
            if (hasNext) {
                const int nt = t + 1, nct = nt >> 3, nks = nt & 7;
                #pragma unroll
                for (int q = 0; q < 4; ++q) {
                    int id = q * 256 + tid;
                    int half = id >> 9, rem = id & 511, cl = rem >> 2, pc = rem & 3;
                    int clog = pc ^ ((cl >> 1) & 3);
                    sb[q] = *reinterpret_cast<const u16x8*>(
                        e16 + (size_t)(half * 512 + nct * 128 + cl) * DDIM + nks * 32 + clog * 8);
                }
            }

            if (ct == 0) {
                #pragma unroll
                for (int m = 0; m < 2; ++m) {
                    const float* zp = z + (size_t)(rowbase + 16 * m + ll) * DDIM + ks * 32 + lg * 8;
                    float4 p0 = *reinterpret_cast<const float4*>(zp);
                    float4 p1 = *reinterpret_cast<const float4*>(zp + 4);
                    float fv[8] = {p0.x, p0.y, p0.z, p0.w, p1.x, p1.y, p1.z, p1.w};
                    #pragma unroll
                    for (int e = 0; e < 8; ++e) afrag[ks][m][e] = (_Float16)fv[e];
                }
            }

            #pragma unroll
            for (int n = 0; n < 8; ++n) {
                f16x8 bh = *reinterpret_cast<const f16x8*>(
                    &Bt[buf][codeHalf][n * 512 + rdbase]);
                #pragma unroll
                for (int m = 0; m < 2; ++m)
                    acc[m][n] = __builtin_amdgcn_mfma_f32_16x16x32_f16(
                        afrag[ks][m], bh, acc[m][n], 0, 0, 0);
            }

            if (ks == 7) {
                #pragma unroll
                for (int n = 0; n < 8; ++n) {
                    const int c = chbase + ct * 128 + n * 16 + ll;
                    const float s2v = s2s[c];
                    #pragma unroll
                    for (int m = 0; m < 2; ++m)
                        #pragma unroll
                        for (int j = 0; j < 4; ++j) {
                            float v = fmaf(-0.001953125f, acc[m][n][j], s2v);
                            if (v < bv[m][j] || (v == bv[m][j] && c < bk[m][j])) {
                                sv[m][j] = bv[m][j]; bv[m][j] = v; bk[m][j] = c;
                            } else {
                                sv[m][j] = fminf(sv[m][j], v);
                            }
                        }
                }
            }

            if (hasNext) {
                const int nbuf = buf ^ 1;
                #pragma unroll
                for (int q = 0; q < 4; ++q) {
                    int id = q * 256 + tid;
                    int half = id >> 9, rem = id & 511, cl = rem >> 2, pc = rem & 3;
                    *reinterpret_cast<u16x8*>(&Bt[nbuf][half][cl * 32 + pc * 8]) = sb[q];
                }
            }
            __syncthreads();
        }
    }

    #pragma unroll
    for (int off = 1; off < 16; off <<= 1) {
        #pragma unroll
        for (int m = 0; m < 2; ++m)
            #pragma unroll
            for (int j = 0; j < 4; ++j) {
                float ob = __shfl_xor(bv[m][j], off, 64);
                int   ok = __shfl_xor(bk[m][j], off, 64);
                float os = __shfl_xor(sv[m][j], off, 64);
                if (ob < bv[m][j] || (ob == bv[m][j] && ok < bk[m][j])) {
                    sv[m][j] = fminf(bv[m][j], os); bv[m][j] = ob; bk[m][j] = ok;
                } else {
                    sv[m][j] = fminf(sv[m][j], ob);
                }
            }
    }

    if (ll == 0) {
        #pragma unroll
        for (int m = 0; m < 2; ++m)
            #pragma unroll
            for (int j = 0; j < 4; ++j) {
                int rib = rowHalf * 32 + 16 * m + lg * 4 + j;
                Lbv[codeHalf][rib] = bv[m][j];
                Lsv[codeHalf][rib] = sv[m][j];
                Lbk[codeHalf][rib] = bk[m][j];
            }
    }
    __syncthreads();

    if (tid < 64) {
        const int r = blockIdx.x * 64 + tid;
        if (r < N) {
            float b0 = Lbv[0][tid], s0 = Lsv[0][tid]; int k0 = Lbk[0][tid];
            float b1 = Lbv[1][tid], s1 = Lsv[1][tid]; int k1 = Lbk[1][tid];
            float bb, ss; int kk;
            if (b1 < b0) { bb = b1; kk = k1; ss = fminf(s1, b0); }
            else         { bb = b0; kk = k0; ss = fminf(s0, b1); }
            out[r] = kk;
            if (ss - bb <= TAU) {
                int pos = atomicAdd(count, 1);
                if (pos < LISTCAP) list[pos] = r;
            }
        }
    }
}

// ------- pass 2: wave-per-row fp16 scan + exact window (LOCKED recipe) -------
__global__ __launch_bounds__(256) void vq_pass2(
    const float* __restrict__ z, const float* __restrict__ emb,
    const unsigned short* __restrict__ e16, const float* __restrict__ s2g,
    const int* __restrict__ count, const int* __restrict__ list,
    int* __restrict__ out)
{
#pragma clang fp contract(off)
    __shared__ float vls[4][KCODES];   // 16 KB, wave-private v values
    __shared__ float zls[4][DDIM];     //  4 KB, wave-private z row (fp32)
    __shared__ float s2s[KCODES];      //  4 KB
    __shared__ int   candc[4][CANDCAP];
    __shared__ int   ncand[4];

    const int tid  = threadIdx.x;
    const int wv   = tid >> 6, lane = tid & 63;
    const int lg16 = lane & 15;        // dim-block owner (16 dims each)
    const int grp  = lane >> 4;        // code subgroup 0..3

    for (int c = tid; c < KCODES; c += 256) s2s[c] = s2g[c];
    __syncthreads();

    int cnt = *count; if (cnt > LISTCAP) cnt = LISTCAP;

    for (int idx = blockIdx.x * 4 + wv; idx < cnt; idx += gridDim.x * 4) {
        const int row = list[idx];

        // stage z row (fp32) for exact eval + s1
        *reinterpret_cast<float4*>(&zls[wv][lane * 4]) =
            *reinterpret_cast<const float4*>(z + (size_t)row * DDIM + lane * 4);

        // per-lane fp16 z fragment: dims lg16*16 .. +15
        h2 z16[8];
        {
            const float* zp = z + (size_t)row * DDIM + lg16 * 16;
            #pragma unroll
            for (int q = 0; q < 4; ++q) {
                float4 f = *reinterpret_cast<const float4*>(zp + q * 4);
                h2 a; a[0] = (_Float16)f.x; a[1] = (_Float16)f.y;
                h2 b; b[0] = (_Float16)f.z; b[1] = (_Float16)f.w;
                z16[2 * q] = a; z16[2 * q + 1] = b;
            }
        }
        if (lane == 0) ncand[wv] = 0;

        // ---- fp16 scan: 4 codes/iter, 16 lanes per code ----
        float bv = 3.4e38f; int bk = 0;
        for (int cb = 0; cb < KCODES; cb += 4) {
            const int c = cb + grp;
            const f16x8* ep = reinterpret_cast<const f16x8*>(
                e16 + (size_t)c * DDIM + lg16 * 16);
            f16x8 e0 = ep[0], e1 = ep[1];
            float p = 0.f;
            #pragma unroll
            for (int q = 0; q < 4; ++q) {
                h2 ea; ea[0] = e0[2 * q]; ea[1] = e0[2 * q + 1];
                h2 eb; eb[0] = e1[2 * q]; eb[1] = e1[2 * q + 1];
#if __has_builtin(__builtin_amdgcn_fdot2)
                p = __builtin_amdgcn_fdot2(ea, z16[q], p, false);
                p = __builtin_amdgcn_fdot2(eb, z16[4 + q], p, false);
#else
                p = fmaf((float)ea[0], (float)z16[q][0], p);
                p = fmaf((float)ea[1], (float)z16[q][1], p);
                p = fmaf((float)eb[0], (float)z16[4 + q][0], p);
                p = fmaf((float)eb[1], (float)z16[4 + q][1], p);
#endif
            }
            #pragma unroll
            for (int off = 1; off < 16; off <<= 1)       // sum over 16-lane group
                p += __shfl_xor(p, off, 64);
            float v = fmaf(-0.001953125f, p, s2s[c]);    // v = s2 - dot'/512
            if (lg16 == 0) vls[wv][c] = v;
            if (v < bv) { bv = v; bk = c; }              // ascending c in group
        }
        // merge the 4 code-subgroups (all lanes within a group identical)
        #pragma unroll
        for (int off = 16; off < 64; off <<= 1) {
            float ov = __shfl_xor(bv, off, 64);
            int   ok = __shfl_xor(bk, off, 64);
            if (ov < bv || (ov == bv && ok < bk)) { bv = ov; bk = ok; }
        }

        // ---- candidates: v <= bv + WIN ----
        const float thr = bv + WIN;
        for (int t = 0; t < 16; ++t) {
            float cv = vls[wv][t * 64 + lane];
            if (cv <= thr) {
                int p = atomicAdd(&ncand[wv], 1);
                if (p < CANDCAP) candc[wv][p] = t * 64 + lane;
            }
        }
        int nc = atomicAdd(&ncand[wv], 0);               // ordered read
        if (nc > CANDCAP) nc = CANDCAP;

        // ---- LOCKED exact recipe per candidate ----
        const float* zr = zls[wv];
        const float s1 = block128_sq(zr) + block128_sq(zr + 128);

        float bb = 3.4e38f; int kb = KCODES - 1;
        for (int i = 0; i < nc; ++i) {
            const int c = candc[wv][i];
            float4 ev = *reinterpret_cast<const float4*>(emb + (size_t)c * DDIM + lane * 4);
            const float* zp = &zls[wv][lane * 4];
            double ds = (double)zp[0] * (double)ev.x;
            ds = fma((double)zp[1], (double)ev.y, ds);
            ds = fma((double)zp[2], (double)ev.z, ds);
            ds = fma((double)zp[3], (double)ev.w, ds);
            #pragma unroll
            for (int off = 1; off < 64; off <<= 1)
                ds += __shfl_xor(ds, off, 64);           // exact fp64, order-free
            float twog = 2.0f * (float)ds;               // LOCKED: fl32(2G)
            float t1   = s1 - twog;                      // fp32 rounding 1
            float dv   = t1 + s2s[c];                    // fp32 rounding 2
            if (dv < bb || (dv == bb && c < kb)) { bb = dv; kb = c; }
        }
        if (lane == 0) out[row] = kb;
    }
}

extern "C" void kernel_launch(void* const* d_in, const int* in_sizes, int n_in,
                              void* d_out, int out_size, void* d_ws, size_t ws_size,
                              hipStream_t stream) {
    const float* z   = (const float*)d_in[0];
    const float* emb = (const float*)d_in[1];
    int*   out   = (int*)d_out;
    float* s2    = (float*)d_ws;                                   // 4 KB
    int*   count = (int*)((char*)d_ws + 4096);
    int*   list  = (int*)((char*)d_ws + 4224);                     // 64 KB
    unsigned short* e16 = (unsigned short*)((char*)d_ws + 131072); // 512 KB
    const int N = in_sizes[0] / DDIM;                              // 32768

    vq_prep<<<dim3(128), dim3(256), 0, stream>>>(emb, e16, s2, count);
    vq_pass1<<<dim3(N / 64), dim3(256), 0, stream>>>(z, e16, s2, out, count, list, N);
    vq_pass2<<<dim3(512), dim3(256), 0, stream>>>(z, emb, e16, s2, count, list, out);
}